// Round 2
// baseline (283.067 us; speedup 1.0000x reference)
//
#include <hip/hip_runtime.h>

typedef float  float4v __attribute__((ext_vector_type(4)));
typedef int    int4v   __attribute__((ext_vector_type(4)));

// Defensive scalar read: Python scalars arrive as 1-element arrays whose dtype
// may be int32 or float32. Small int bit patterns are ints; float 1.0f's bit
// pattern (0x3f800000) is a huge int, so fall back to float reinterpretation.
__device__ __forceinline__ float scalar_as_float(const void* p) {
    int iv = *(const int*)p;
    if (iv >= -1000000 && iv <= 1000000) return (float)iv;
    return *(const float*)p;
}
__device__ __forceinline__ int scalar_as_int(const void* p) {
    int iv = *(const int*)p;
    if (iv >= -1000000 && iv <= 1000000) return iv;
    return (int)(*(const float*)p);
}

__global__ __launch_bounds__(256) void rwl_partial_kernel(
        const float* __restrict__ x,
        const int*   __restrict__ idx,
        const void*  __restrict__ target_p,
        const void*  __restrict__ H_p,
        float* __restrict__ partials,
        int n_vec, int n_tail, int n_total)
{
    const float t   = scalar_as_float(target_p);
    const int   mid = scalar_as_int(H_p) >> 1;

    float acc = 0.0f;
    const int tid    = blockIdx.x * blockDim.x + threadIdx.x;
    const int stride = gridDim.x * blockDim.x;

    const float4v* __restrict__ xv4 = (const float4v*)x;
    const int4v*   __restrict__ iv4 = (const int4v*)idx;

    for (int i = tid; i < n_vec; i += stride) {
        float4v xv = xv4[i];
        int4v   iv = iv4[i];
        #pragma unroll
        for (int j = 0; j < 4; ++j) {
            float xx = xv[j];
            float w  = (iv[j] >= mid) ? 2.0f : 1.0f;
            float a  = fabsf(xx);
            // stable BCE-with-logits: max(x,0) - x*t + log(1 + exp(-|x|))
            float bce = fmaxf(xx, 0.0f) - xx * t + __logf(1.0f + __expf(-a));
            acc += w * bce;
        }
    }
    // tail (N not divisible by 4) — handled by global thread 0 only
    if (tid == 0) {
        for (int k = n_vec * 4; k < n_total; ++k) {
            float xx = x[k];
            float w  = (idx[k] >= mid) ? 2.0f : 1.0f;
            float a  = fabsf(xx);
            acc += w * (fmaxf(xx, 0.0f) - xx * t + __logf(1.0f + __expf(-a)));
        }
    }

    // wave-64 butterfly reduce
    #pragma unroll
    for (int off = 32; off > 0; off >>= 1)
        acc += __shfl_down(acc, off, 64);

    __shared__ float smem[4];
    const int lane = threadIdx.x & 63;
    const int wid  = threadIdx.x >> 6;
    if (lane == 0) smem[wid] = acc;
    __syncthreads();
    if (threadIdx.x == 0)
        partials[blockIdx.x] = smem[0] + smem[1] + smem[2] + smem[3];
}

__global__ __launch_bounds__(256) void rwl_final_kernel(
        const float* __restrict__ partials, int n, float inv_total,
        float* __restrict__ out)
{
    float acc = 0.0f;
    for (int i = threadIdx.x; i < n; i += 256) acc += partials[i];
    #pragma unroll
    for (int off = 32; off > 0; off >>= 1)
        acc += __shfl_down(acc, off, 64);
    __shared__ float smem[4];
    const int lane = threadIdx.x & 63;
    const int wid  = threadIdx.x >> 6;
    if (lane == 0) smem[wid] = acc;
    __syncthreads();
    if (threadIdx.x == 0)
        out[0] = (smem[0] + smem[1] + smem[2] + smem[3]) * inv_total;
}

extern "C" void kernel_launch(void* const* d_in, const int* in_sizes, int n_in,
                              void* d_out, int out_size, void* d_ws, size_t ws_size,
                              hipStream_t stream) {
    const float* x      = (const float*)d_in[0];
    const void*  target = d_in[1];
    const int*   idx    = (const int*)d_in[2];
    const void*  Hp     = d_in[3];
    float* out          = (float*)d_out;
    float* partials     = (float*)d_ws;

    const int n_total = in_sizes[0];
    const int n_vec   = n_total >> 2;
    const int n_tail  = n_total & 3;

    // memory-bound: cap grid at ~8 blocks/CU and grid-stride the rest
    int blocks = (n_vec + 255) / 256;
    if (blocks > 2048) blocks = 2048;
    if (blocks < 1)    blocks = 1;

    rwl_partial_kernel<<<blocks, 256, 0, stream>>>(
        x, idx, target, Hp, partials, n_vec, n_tail, n_total);

    const float inv_total = 1.0f / (float)n_total;
    rwl_final_kernel<<<1, 256, 0, stream>>>(partials, blocks, inv_total, out);
}